// Round 1
// baseline (138.573 us; speedup 1.0000x reference)
//
#include <hip/hip_runtime.h>

#define N_DIM 4
#define C_DIM 256
#define T_DIM 5
#define HW    784
#define L_TOK 3920   // T*H*W
#define CI    128
#define CA    128

// ws layout (floats):
//   [0,       5120)  Xs  [N][T][C]
//   [5120,   10240)  TP  [N][T][C]
//   [10240,  15360)  GW2 [N][T][C]   (Wz_W @ G * bn_inv / L folded)
//   [15360,  15380)  tb  [N][T]
#define WS_XS  0
#define WS_TP  5120
#define WS_GW  10240
#define WS_TB  15360

// ---------------- kernel 1: Xs[n,t,c] = sum_{h,w} x[n,c,t,h,w] ----------------
__global__ __launch_bounds__(256) void k1_xsum(const float* __restrict__ x,
                                               float* __restrict__ ws) {
    int bid = blockIdx.x;                 // n*(C*T) + c*T + t
    int n   = bid / (C_DIM * T_DIM);
    int rem = bid % (C_DIM * T_DIM);
    int c   = rem / T_DIM;
    int t   = rem % T_DIM;
    const float* base = x + ((size_t)(n * C_DIM + c) * T_DIM + t) * HW;
    int tid = threadIdx.x;

    float p = base[tid] + base[tid + 256] + base[tid + 512];
    if (tid < HW - 768) p += base[tid + 768];

    for (int off = 32; off > 0; off >>= 1) p += __shfl_down(p, off, 64);
    __shared__ float wsum[4];
    if ((tid & 63) == 0) wsum[tid >> 6] = p;
    __syncthreads();
    if (tid == 0) {
        ws[WS_XS + (n * T_DIM + t) * C_DIM + c] = wsum[0] + wsum[1] + wsum[2] + wsum[3];
    }
}

// ------------- kernel 2: tiny per-(n,t) chain: audio_temp, phiT, TP, tb, G, GW2 -------------
__global__ __launch_bounds__(256) void k2_small(
    const float* __restrict__ audio,   const float* __restrict__ align_W,
    const float* __restrict__ align_b, const float* __restrict__ g_W,
    const float* __restrict__ g_b,     const float* __restrict__ theta_W,
    const float* __restrict__ theta_b, const float* __restrict__ phi_W,
    const float* __restrict__ phi_b,   const float* __restrict__ Wz_W,
    const float* __restrict__ bn_gamma,const float* __restrict__ bn_var,
    float* __restrict__ ws, float* __restrict__ out_audio) {
    int nt = blockIdx.x;                  // n*T + t
    int tid = threadIdx.x;

    __shared__ float at_s[C_DIM];
    __shared__ float xs_s[C_DIM];
    __shared__ float phi_s[CI];
    __shared__ float g_s[CI];

    // audio_temp[nt, c] = audio[nt,:] . align_W[c,:] + align_b[c]
    {
        const float* arow = audio + nt * CA;
        const float* wrow = align_W + tid * CA;
        float acc = align_b[tid];
        for (int a = 0; a < CA; ++a) acc = fmaf(arow[a], wrow[a], acc);
        at_s[tid] = acc;
        out_audio[nt * C_DIM + tid] = acc;   // second output of the tuple
    }
    xs_s[tid] = ws[WS_XS + nt * C_DIM + tid];
    __syncthreads();

    if (tid < CI) {
        // phiT[o] = phi_W[o,:] . audio_temp + phi_b[o]
        float acc = phi_b[tid];
        const float* wrow = phi_W + tid * C_DIM;
        for (int c = 0; c < C_DIM; ++c) acc = fmaf(wrow[c], at_s[c], acc);
        phi_s[tid] = acc;
        // G[o] = g_W[o,:] . Xs + HW*g_b[o]
        float ga = (float)HW * g_b[tid];
        const float* grow = g_W + tid * C_DIM;
        for (int c = 0; c < C_DIM; ++c) ga = fmaf(grow[c], xs_s[c], ga);
        g_s[tid] = ga;
    }
    __syncthreads();

    // TP[c] = sum_o theta_W[o,c] * phiT[o]
    {
        float acc = 0.f;
        for (int o = 0; o < CI; ++o) acc = fmaf(theta_W[o * C_DIM + tid], phi_s[o], acc);
        ws[WS_TP + nt * C_DIM + tid] = acc;
    }
    // tb = sum_o theta_b[o] * phiT[o]
    if (tid == 0) {
        float acc = 0.f;
        for (int o = 0; o < CI; ++o) acc = fmaf(theta_b[o], phi_s[o], acc);
        ws[WS_TB + nt] = acc;
    }
    // GW2[c] = (Wz_W[c,:] . G) * bn_inv[c] / L
    {
        float acc = 0.f;
        const float* wr = Wz_W + tid * CI;
        for (int o = 0; o < CI; ++o) acc = fmaf(wr[o], g_s[o], acc);
        float inv = bn_gamma[tid] * rsqrtf(bn_var[tid] + 1e-5f);
        ws[WS_GW + nt * C_DIM + tid] = acc * inv * (1.0f / (float)L_TOK);
    }
}

// ------------- kernel 3: fused F + epilogue + residual + LayerNorm -------------
// block: 256 thr = 4 c-groups x 64 tokens; grid: (62 tiles, N)
__global__ __launch_bounds__(256) void k3_main(
    const float* __restrict__ x,        const float* __restrict__ ws,
    const float* __restrict__ Wz_b,     const float* __restrict__ bn_gamma,
    const float* __restrict__ bn_beta,  const float* __restrict__ bn_mean,
    const float* __restrict__ bn_var,   const float* __restrict__ ln_gamma,
    const float* __restrict__ ln_beta,  float* __restrict__ out) {
    __shared__ float TPs[T_DIM * C_DIM];
    __shared__ float GWs[T_DIM * C_DIM];
    __shared__ float tb_s[T_DIM];
    __shared__ float B_s[C_DIM], lng_s[C_DIM], lnb_s[C_DIM];
    __shared__ float zbuf[64 * 257];          // x tile, then z tile in-place
    __shared__ float Fp[256 * 5];
    __shared__ float Sp[256 * 2];

    int n    = blockIdx.y;
    int tile = blockIdx.x;
    int tid  = threadIdx.x;
    int g    = tid >> 6;        // channel group 0..3 (== wave id)
    int li   = tid & 63;        // token within tile
    int l    = tile * 64 + li;
    bool act = (l < L_TOK);

    for (int i = tid; i < T_DIM * C_DIM; i += 256) {
        TPs[i] = ws[WS_TP + n * T_DIM * C_DIM + i];
        GWs[i] = ws[WS_GW + n * T_DIM * C_DIM + i];
    }
    if (tid < T_DIM) tb_s[tid] = ws[WS_TB + n * T_DIM + tid];
    {
        int c = tid;
        float inv = bn_gamma[c] * rsqrtf(bn_var[c] + 1e-5f);
        B_s[c]   = (Wz_b[c] - bn_mean[c]) * inv + bn_beta[c];
        lng_s[c] = ln_gamma[c];
        lnb_s[c] = ln_beta[c];
    }
    __syncthreads();

    // phase 1: load x tile, accumulate F[t] partials over this group's 64 channels
    float F0 = 0, F1 = 0, F2 = 0, F3 = 0, F4 = 0;
    const float* xb = x + ((size_t)n * C_DIM + g * 64) * L_TOK + l;
    float* zrow = zbuf + li * 257 + g * 64;
    if (act) {
        for (int j = 0; j < 64; ++j) {
            float xv = xb[j * L_TOK];
            zrow[j] = xv;
            const float* tp = TPs + g * 64 + j;
            F0 = fmaf(xv, tp[0],    F0);
            F1 = fmaf(xv, tp[256],  F1);
            F2 = fmaf(xv, tp[512],  F2);
            F3 = fmaf(xv, tp[768],  F3);
            F4 = fmaf(xv, tp[1024], F4);
        }
    }
    Fp[tid * 5 + 0] = F0; Fp[tid * 5 + 1] = F1; Fp[tid * 5 + 2] = F2;
    Fp[tid * 5 + 3] = F3; Fp[tid * 5 + 4] = F4;
    __syncthreads();

    // phase 2: full F per token, compute z over this group's channels, stats
    float Ft[T_DIM];
    #pragma unroll
    for (int t = 0; t < T_DIM; ++t)
        Ft[t] = Fp[(0 * 64 + li) * 5 + t] + Fp[(1 * 64 + li) * 5 + t] +
                Fp[(2 * 64 + li) * 5 + t] + Fp[(3 * 64 + li) * 5 + t] + tb_s[t];
    float s1 = 0.f, s2 = 0.f;
    for (int j = 0; j < 64; ++j) {
        int c = g * 64 + j;
        float zc = B_s[c] + zrow[j];
        zc = fmaf(Ft[0], GWs[c],        zc);
        zc = fmaf(Ft[1], GWs[256 + c],  zc);
        zc = fmaf(Ft[2], GWs[512 + c],  zc);
        zc = fmaf(Ft[3], GWs[768 + c],  zc);
        zc = fmaf(Ft[4], GWs[1024 + c], zc);
        zrow[j] = zc;
        s1 += zc;
        s2 = fmaf(zc, zc, s2);
    }
    Sp[tid * 2]     = s1;
    Sp[tid * 2 + 1] = s2;
    __syncthreads();

    // phase 3: LayerNorm over channels, write out
    float t1 = Sp[li * 2]     + Sp[(64 + li) * 2]     + Sp[(128 + li) * 2]     + Sp[(192 + li) * 2];
    float t2 = Sp[li * 2 + 1] + Sp[(64 + li) * 2 + 1] + Sp[(128 + li) * 2 + 1] + Sp[(192 + li) * 2 + 1];
    float mu   = t1 * (1.0f / C_DIM);
    float var  = t2 * (1.0f / C_DIM) - mu * mu;
    float rstd = rsqrtf(var + 1e-5f);
    if (act) {
        float* ob = out + ((size_t)n * C_DIM + g * 64) * L_TOK + l;
        for (int j = 0; j < 64; ++j) {
            int c = g * 64 + j;
            float zc = zrow[j];
            ob[j * L_TOK] = fmaf((zc - mu) * rstd, lng_s[c], lnb_s[c]);
        }
    }
}

extern "C" void kernel_launch(void* const* d_in, const int* in_sizes, int n_in,
                              void* d_out, int out_size, void* d_ws, size_t ws_size,
                              hipStream_t stream) {
    const float* x        = (const float*)d_in[0];
    const float* audio    = (const float*)d_in[1];
    const float* align_W  = (const float*)d_in[2];
    const float* align_b  = (const float*)d_in[3];
    const float* g_W      = (const float*)d_in[4];
    const float* g_b      = (const float*)d_in[5];
    const float* theta_W  = (const float*)d_in[6];
    const float* theta_b  = (const float*)d_in[7];
    const float* phi_W    = (const float*)d_in[8];
    const float* phi_b    = (const float*)d_in[9];
    const float* Wz_W     = (const float*)d_in[10];
    const float* Wz_b     = (const float*)d_in[11];
    const float* bn_gamma = (const float*)d_in[12];
    const float* bn_beta  = (const float*)d_in[13];
    const float* bn_mean  = (const float*)d_in[14];
    const float* bn_var   = (const float*)d_in[15];
    const float* ln_gamma = (const float*)d_in[16];
    const float* ln_beta  = (const float*)d_in[17];

    float* out       = (float*)d_out;
    float* out_audio = out + (size_t)N_DIM * C_DIM * L_TOK;   // 4,014,080
    float* ws        = (float*)d_ws;

    k1_xsum<<<N_DIM * C_DIM * T_DIM, 256, 0, stream>>>(x, ws);
    k2_small<<<N_DIM * T_DIM, 256, 0, stream>>>(
        audio, align_W, align_b, g_W, g_b, theta_W, theta_b, phi_W, phi_b,
        Wz_W, bn_gamma, bn_var, ws, out_audio);
    dim3 grid3((L_TOK + 63) / 64, N_DIM);
    k3_main<<<grid3, 256, 0, stream>>>(
        x, ws, Wz_b, bn_gamma, bn_beta, bn_mean, bn_var, ln_gamma, ln_beta, out);
}

// Round 3
// 135.976 us; speedup vs baseline: 1.0191x; 1.0191x over previous
//
#include <hip/hip_runtime.h>

#define N_DIM 4
#define C_DIM 256
#define T_DIM 5
#define HW    784
#define L_TOK 3920   // T*H*W
#define CI    128
#define CA    128

// ws layout (floats):
//   [0,       5120)  Xs  [N][T][C]
//   [5120,   10240)  TP  [N][T][C]
//   [10240,  15360)  GW2 [N][T][C]   (Wz_W @ G * bn_inv / L folded)
//   [15360,  15380)  tb  [N][T]
#define WS_XS  0
#define WS_TP  5120
#define WS_GW  10240
#define WS_TB  15360

// ---------------- kernel 1: Xs[n,t,c] = sum_{h,w} x[n,c,t,h,w] ----------------
// one block per (n,c,t): 784 floats = 196 float4, thread tid<196 loads one.
__global__ __launch_bounds__(256) void k1_xsum(const float* __restrict__ x,
                                               float* __restrict__ ws) {
    int bid = blockIdx.x;                 // n*(C*T) + c*T + t
    int n   = bid / (C_DIM * T_DIM);
    int rem = bid % (C_DIM * T_DIM);
    int c   = rem / T_DIM;
    int t   = rem % T_DIM;
    const float4* base = (const float4*)(x + ((size_t)(n * C_DIM + c) * T_DIM + t) * HW);
    int tid = threadIdx.x;

    float p = 0.f;
    if (tid < HW / 4) {
        float4 v = base[tid];
        p = (v.x + v.y) + (v.z + v.w);
    }
    for (int off = 32; off > 0; off >>= 1) p += __shfl_down(p, off, 64);
    __shared__ float wsum[4];
    if ((tid & 63) == 0) wsum[tid >> 6] = p;
    __syncthreads();
    if (tid == 0) {
        ws[WS_XS + (n * T_DIM + t) * C_DIM + c] = wsum[0] + wsum[1] + wsum[2] + wsum[3];
    }
}

// ------------- kernel 2: tiny per-(n,t) chain -------------
// float4 row loads + 4 accumulators; shared vectors staged in LDS.
__global__ __launch_bounds__(256) void k2_small(
    const float* __restrict__ audio,   const float* __restrict__ align_W,
    const float* __restrict__ align_b, const float* __restrict__ g_W,
    const float* __restrict__ g_b,     const float* __restrict__ theta_W,
    const float* __restrict__ theta_b, const float* __restrict__ phi_W,
    const float* __restrict__ phi_b,   const float* __restrict__ Wz_W,
    const float* __restrict__ bn_gamma,const float* __restrict__ bn_var,
    float* __restrict__ ws, float* __restrict__ out_audio) {
    int nt = blockIdx.x;                  // n*T + t
    int tid = threadIdx.x;

    __shared__ float audio_s[CA];
    __shared__ float at_s[C_DIM];
    __shared__ float xs_s[C_DIM];
    __shared__ float phi_s[CI];
    __shared__ float g_s[CI];

    if (tid < CA) audio_s[tid] = audio[nt * CA + tid];
    xs_s[tid] = ws[WS_XS + nt * C_DIM + tid];
    __syncthreads();

    // audio_temp[c] = audio . align_W[c,:] + align_b[c]
    {
        const float4* row = (const float4*)(align_W + tid * CA);
        float a0 = 0, a1 = 0, a2 = 0, a3 = 0;
        #pragma unroll
        for (int k = 0; k < CA / 4; ++k) {
            float4 w = row[k];
            a0 = fmaf(w.x, audio_s[4 * k + 0], a0);
            a1 = fmaf(w.y, audio_s[4 * k + 1], a1);
            a2 = fmaf(w.z, audio_s[4 * k + 2], a2);
            a3 = fmaf(w.w, audio_s[4 * k + 3], a3);
        }
        float acc = align_b[tid] + (a0 + a1) + (a2 + a3);
        at_s[tid] = acc;
        out_audio[nt * C_DIM + tid] = acc;   // second tuple output
    }
    __syncthreads();

    if (tid < CI) {
        // phiT[o] = phi_W[o,:] . audio_temp + phi_b[o]
        const float4* prow = (const float4*)(phi_W + tid * C_DIM);
        const float4* grow = (const float4*)(g_W + tid * C_DIM);
        float p0 = 0, p1 = 0, p2 = 0, p3 = 0;
        float q0 = 0, q1 = 0, q2 = 0, q3 = 0;
        #pragma unroll
        for (int k = 0; k < C_DIM / 4; ++k) {
            float4 w = prow[k];
            float4 u = grow[k];
            float b0 = at_s[4 * k + 0], b1 = at_s[4 * k + 1];
            float b2 = at_s[4 * k + 2], b3 = at_s[4 * k + 3];
            float c0 = xs_s[4 * k + 0], c1 = xs_s[4 * k + 1];
            float c2 = xs_s[4 * k + 2], c3 = xs_s[4 * k + 3];
            p0 = fmaf(w.x, b0, p0); p1 = fmaf(w.y, b1, p1);
            p2 = fmaf(w.z, b2, p2); p3 = fmaf(w.w, b3, p3);
            q0 = fmaf(u.x, c0, q0); q1 = fmaf(u.y, c1, q1);
            q2 = fmaf(u.z, c2, q2); q3 = fmaf(u.w, c3, q3);
        }
        phi_s[tid] = phi_b[tid] + (p0 + p1) + (p2 + p3);
        g_s[tid]   = (float)HW * g_b[tid] + (q0 + q1) + (q2 + q3);
    }
    __syncthreads();

    // TP[c] = sum_o theta_W[o,c] * phiT[o]   (coalesced along tid)
    {
        float a0 = 0, a1 = 0, a2 = 0, a3 = 0;
        #pragma unroll 4
        for (int o = 0; o < CI; o += 4) {
            a0 = fmaf(theta_W[(o + 0) * C_DIM + tid], phi_s[o + 0], a0);
            a1 = fmaf(theta_W[(o + 1) * C_DIM + tid], phi_s[o + 1], a1);
            a2 = fmaf(theta_W[(o + 2) * C_DIM + tid], phi_s[o + 2], a2);
            a3 = fmaf(theta_W[(o + 3) * C_DIM + tid], phi_s[o + 3], a3);
        }
        ws[WS_TP + nt * C_DIM + tid] = (a0 + a1) + (a2 + a3);
    }
    // tb = theta_b . phiT  (wave 0, lane-parallel)
    if (tid < 64) {
        float p = theta_b[tid] * phi_s[tid] + theta_b[tid + 64] * phi_s[tid + 64];
        for (int off = 32; off > 0; off >>= 1) p += __shfl_down(p, off, 64);
        if (tid == 0) ws[WS_TB + nt] = p;
    }
    // GW2[c] = (Wz_W[c,:] . G) * bn_inv[c] / L
    {
        const float4* row = (const float4*)(Wz_W + tid * CI);
        float a0 = 0, a1 = 0, a2 = 0, a3 = 0;
        #pragma unroll
        for (int k = 0; k < CI / 4; ++k) {
            float4 w = row[k];
            a0 = fmaf(w.x, g_s[4 * k + 0], a0);
            a1 = fmaf(w.y, g_s[4 * k + 1], a1);
            a2 = fmaf(w.z, g_s[4 * k + 2], a2);
            a3 = fmaf(w.w, g_s[4 * k + 3], a3);
        }
        float inv = bn_gamma[tid] * rsqrtf(bn_var[tid] + 1e-5f);
        ws[WS_GW + nt * C_DIM + tid] = ((a0 + a1) + (a2 + a3)) * inv * (1.0f / (float)L_TOK);
    }
}

// ------------- kernel 3: fused F + epilogue + residual + LayerNorm -------------
// block: 1024 thr = 16 groups x 64 tokens; x/z tile lives in 16 regs/thread.
__global__ __launch_bounds__(1024) void k3_main(
    const float* __restrict__ x,        const float* __restrict__ ws,
    const float* __restrict__ Wz_b,     const float* __restrict__ bn_gamma,
    const float* __restrict__ bn_beta,  const float* __restrict__ bn_mean,
    const float* __restrict__ bn_var,   const float* __restrict__ ln_gamma,
    const float* __restrict__ ln_beta,  float* __restrict__ out) {
    __shared__ float TPs[T_DIM * C_DIM];
    __shared__ float GWs[T_DIM * C_DIM];
    __shared__ float tb_s[T_DIM];
    __shared__ float B_s[C_DIM], lng_s[C_DIM], lnb_s[C_DIM];
    __shared__ float Fp[T_DIM * 1024];     // [t][group][token]
    __shared__ float Sp[2 * 1024];         // [2][group][token]

    int n    = blockIdx.y;
    int tile = blockIdx.x;
    int tid  = threadIdx.x;
    int g    = tid >> 6;        // channel group 0..15 (== wave id)
    int li   = tid & 63;        // token within tile
    int l    = tile * 64 + li;
    bool act = (l < L_TOK);

    for (int i = tid; i < T_DIM * C_DIM; i += 1024) {
        TPs[i] = ws[WS_TP + n * T_DIM * C_DIM + i];
        GWs[i] = ws[WS_GW + n * T_DIM * C_DIM + i];
    }
    if (tid < T_DIM) tb_s[tid] = ws[WS_TB + n * T_DIM + tid];
    if (tid < C_DIM) {
        int c = tid;
        float inv = bn_gamma[c] * rsqrtf(bn_var[c] + 1e-5f);
        B_s[c]   = (Wz_b[c] - bn_mean[c]) * inv + bn_beta[c];
        lng_s[c] = ln_gamma[c];
        lnb_s[c] = ln_beta[c];
    }
    __syncthreads();

    // phase 1: load 16 channels of token l into regs; F[t] partials
    float xz[16];
    const float* xb = x + ((size_t)(n * C_DIM + g * 16)) * L_TOK + l;
    #pragma unroll
    for (int j = 0; j < 16; ++j) xz[j] = act ? xb[(size_t)j * L_TOK] : 0.f;

    float F0 = 0, F1 = 0, F2 = 0, F3 = 0, F4 = 0;
    #pragma unroll
    for (int j = 0; j < 16; ++j) {
        const float* tp = TPs + g * 16 + j;
        F0 = fmaf(xz[j], tp[0],    F0);
        F1 = fmaf(xz[j], tp[256],  F1);
        F2 = fmaf(xz[j], tp[512],  F2);
        F3 = fmaf(xz[j], tp[768],  F3);
        F4 = fmaf(xz[j], tp[1024], F4);
    }
    Fp[0 * 1024 + tid] = F0; Fp[1 * 1024 + tid] = F1; Fp[2 * 1024 + tid] = F2;
    Fp[3 * 1024 + tid] = F3; Fp[4 * 1024 + tid] = F4;
    __syncthreads();

    // phase 2: full F per token (sum over 16 groups), z over own channels, stats
    float Ft[T_DIM];
    #pragma unroll
    for (int t = 0; t < T_DIM; ++t) {
        float a = tb_s[t];
        #pragma unroll
        for (int w = 0; w < 16; ++w) a += Fp[t * 1024 + w * 64 + li];
        Ft[t] = a;
    }
    float s1 = 0.f, s2 = 0.f;
    #pragma unroll
    for (int j = 0; j < 16; ++j) {
        int c = g * 16 + j;
        float zc = B_s[c] + xz[j];
        zc = fmaf(Ft[0], GWs[c],        zc);
        zc = fmaf(Ft[1], GWs[256 + c],  zc);
        zc = fmaf(Ft[2], GWs[512 + c],  zc);
        zc = fmaf(Ft[3], GWs[768 + c],  zc);
        zc = fmaf(Ft[4], GWs[1024 + c], zc);
        xz[j] = zc;
        s1 += zc;
        s2 = fmaf(zc, zc, s2);
    }
    Sp[tid]        = s1;
    Sp[1024 + tid] = s2;
    __syncthreads();

    // phase 3: LayerNorm over channels, write out
    float t1 = 0.f, t2 = 0.f;
    #pragma unroll
    for (int w = 0; w < 16; ++w) {
        t1 += Sp[w * 64 + li];
        t2 += Sp[1024 + w * 64 + li];
    }
    float mu   = t1 * (1.0f / C_DIM);
    float var  = t2 * (1.0f / C_DIM) - mu * mu;
    float rstd = rsqrtf(var + 1e-5f);
    if (act) {
        float* ob = out + ((size_t)(n * C_DIM + g * 16)) * L_TOK + l;
        #pragma unroll
        for (int j = 0; j < 16; ++j) {
            int c = g * 16 + j;
            ob[(size_t)j * L_TOK] = fmaf((xz[j] - mu) * rstd, lng_s[c], lnb_s[c]);
        }
    }
}

extern "C" void kernel_launch(void* const* d_in, const int* in_sizes, int n_in,
                              void* d_out, int out_size, void* d_ws, size_t ws_size,
                              hipStream_t stream) {
    const float* x        = (const float*)d_in[0];
    const float* audio    = (const float*)d_in[1];
    const float* align_W  = (const float*)d_in[2];
    const float* align_b  = (const float*)d_in[3];
    const float* g_W      = (const float*)d_in[4];
    const float* g_b      = (const float*)d_in[5];
    const float* theta_W  = (const float*)d_in[6];
    const float* theta_b  = (const float*)d_in[7];
    const float* phi_W    = (const float*)d_in[8];
    const float* phi_b    = (const float*)d_in[9];
    const float* Wz_W     = (const float*)d_in[10];
    const float* Wz_b     = (const float*)d_in[11];
    const float* bn_gamma = (const float*)d_in[12];
    const float* bn_beta  = (const float*)d_in[13];
    const float* bn_mean  = (const float*)d_in[14];
    const float* bn_var   = (const float*)d_in[15];
    const float* ln_gamma = (const float*)d_in[16];
    const float* ln_beta  = (const float*)d_in[17];

    float* out       = (float*)d_out;
    float* out_audio = out + (size_t)N_DIM * C_DIM * L_TOK;   // 4,014,080
    float* ws        = (float*)d_ws;

    k1_xsum<<<N_DIM * C_DIM * T_DIM, 256, 0, stream>>>(x, ws);
    k2_small<<<N_DIM * T_DIM, 256, 0, stream>>>(
        audio, align_W, align_b, g_W, g_b, theta_W, theta_b, phi_W, phi_b,
        Wz_W, bn_gamma, bn_var, ws, out_audio);
    dim3 grid3((L_TOK + 63) / 64, N_DIM);
    k3_main<<<grid3, 1024, 0, stream>>>(
        x, ws, Wz_b, bn_gamma, bn_beta, bn_mean, bn_var, ln_gamma, ln_beta, out);
}